// Round 22
// baseline (305.184 us; speedup 1.0000x reference)
//
#include <hip/hip_runtime.h>
#include <hip/hip_bf16.h>
#include <cstdint>

#define DI __device__ __forceinline__

using bf16x8 = __attribute__((ext_vector_type(8))) short;
using f32x4  = __attribute__((ext_vector_type(4))) float;

constexpr int IN_DIM = 384;
constexpr int HID    = 512;
constexpr int KTOT   = IN_DIM * 20;          // 7680: k = i*20 + t
constexpr int BM = 64, BN = 512, BK = 160;   // 8 input dims per K-step; BN = full HID
constexpr int NSTEP = KTOT / BK;             // 48
// R21 champion + two zero-register scheduling levers:
//  (a) wave-phase stagger: odd waves COMPUTE->AGEN, even waves AGEN->COMPUTE (both orders
//      data-independent: AGEN writes parity s+1, COMPUTE reads parity s) -> VALU and MFMA
//      phases interleave across waves instead of lockstepping;
//  (b) s_setprio(1) around the compute cluster (T5: pays when wave roles diverge).
constexpr int A_STRIDE_B = 320;
constexpr int A_BYTES    = BM * A_STRIDE_B;        // 20480
constexpr int LDS_BYTES  = 2 * A_BYTES;            // 40960 -> 2 blocks/CU (16 waves)

DI unsigned short f2bf(float f) {
  union { float f; uint32_t u; } v; v.f = f;
  uint32_t r = (v.u + 0x7FFFu + ((v.u >> 16) & 1u)) >> 16;
  return (unsigned short)r;
}
DI float fast_tanh(float x) {
  float e = __expf(2.0f * x);
  return 1.0f - 2.0f / (e + 1.0f);
}
DI uint32_t swzw(uint32_t L) { return L ^ ((L >> 6) & 0x70u); }

// ---------------- kpack: W -> bf16 fragment-linear Wf (16x16x32 layout, R18-verbatim) ----
__global__ __launch_bounds__(256) void kpack(const float* __restrict__ bw,
                                             const float* __restrict__ sw,
                                             unsigned short* __restrict__ Wf) {
  int idx = blockIdx.x * 256 + threadIdx.x;   // o*384 + i
  int o = idx / IN_DIM;
  int i = idx - o * IN_DIM;
  const float* sp = sw + (size_t)idx * 19;
  const uint32_t gq  = (uint32_t)(o >> 4);
  const uint32_t l16o = (uint32_t)(o & 15);
#pragma unroll
  for (int c = 0; c < 20; ++c) {
    int k = i * 20 + c;
    uint32_t q  = (uint32_t)k >> 5;
    uint32_t kr = (uint32_t)k & 31u;
    uint32_t lane = l16o + ((kr >> 3) << 4);
    uint32_t off = (q * 32u + gq) * 512u + lane * 8u + (kr & 7u);
    float v = (c == 0) ? bw[idx] : sp[c - 1];
    Wf[off] = f2bf(v);
  }
}

// ---------------- fused KAN GEMM: h = tanh(A(x) @ W^T), 8 waves, wave tile 64x64 ----------------
__global__ __launch_bounds__(512, 4) void kgemm1(const float* __restrict__ z,
                                                 const float* __restrict__ ms,
                                                 const float* __restrict__ md,
                                                 const unsigned short* __restrict__ Wf,
                                                 unsigned short* __restrict__ hout) {
  extern __shared__ char ldsbuf[];            // [A0 @0][A1 @20480]

  const int tid  = threadIdx.x;
  const int lane = tid & 63;
  const int wv   = tid >> 6;                  // 0..7
  const int wc   = wv;                        // N strip (64 cols); all waves share rows
  const int l16  = lane & 15;
  const int lhi  = lane >> 4;

  // XCD-aware bijective swizzle: grid 512 = 8 XCD * 64 (pure M split; every block scans W)
  int wg = blockIdx.x;
  int id = (wg & 7) * 64 + (wg >> 3);
  const int row0 = id * BM;

  // B global fragment base: g = wc*4 + ni in [0,32); q = s*5 + ks (frag stride 16384 elems)
  const unsigned short* bpt = Wf + (size_t)(wc * 4) * 512 + (size_t)lane * 8;

  // A-gen: exactly ONE task per thread (64 rows x 8 isl = 512)
  const int isl = tid & 7;
  const int arow = tid >> 3;                  // 0..63
  const uint32_t fw = ((uint32_t)arow & 7u) << 4;
  const uint32_t abase = (uint32_t)arow * A_STRIDE_B + (uint32_t)isl * 40u;

  // A fragment read base (XOR applied to full address; R18-verbatim)
  const uint32_t fA = (uint32_t)(l16 & 7) << 4;      // row&7 = l16&7
  const uint32_t rA = (uint32_t)l16 * A_STRIDE_B + (uint32_t)lhi * 16u;

  f32x4 acc[4][4] = {};

  // AGEN(sn, xin): writes A(sn) into parity sn&1 using xin = x(sn); returns x(sn+1).
  auto AGEN = [&](int sn, float xin) -> float {
    char* An = ldsbuf + (uint32_t)(sn & 1) * (uint32_t)A_BYTES;
    float xt = fast_tanh(xin);
    float tt = (xt + 1.0f) * 8.0f;
    int   m  = (int)tt; m = m > 16 ? 16 : m;
    float u  = tt - (float)m;
    float omu = 1.0f - u;
    float u2 = u * u, u3 = u2 * u;
    float w0 = omu * omu * omu * (1.0f / 6.0f);
    float w1 = (3.0f * u3 - 6.0f * u2 + 4.0f) * (1.0f / 6.0f);
    float w2 = (-3.0f * u3 + 3.0f * u2 + 3.0f * u + 1.0f) * (1.0f / 6.0f);
    float w3 = u3 * (1.0f / 6.0f);
    float sil = xt / (1.0f + __expf(-xt));
#pragma unroll
    for (int zz = 0; zz < 5; ++zz)
      *(uint64_t*)(An + ((abase + zz * 8) ^ fw)) = 0ull;
    *(short*)(An + (abase ^ fw)) = (short)f2bf(sil);
    *(short*)(An + ((abase + 2u * (m + 1)) ^ fw)) = (short)f2bf(w0);
    *(short*)(An + ((abase + 2u * (m + 2)) ^ fw)) = (short)f2bf(w1);
    *(short*)(An + ((abase + 2u * (m + 3)) ^ fw)) = (short)f2bf(w2);
    if (m < 16)
      *(short*)(An + ((abase + 2u * (m + 4)) ^ fw)) = (short)f2bf(w3);
    float xnext = 0.f;
    if (sn + 1 < NSTEP) {
      int i = (sn + 1) * 8 + isl;
      const float* src = (i < 128) ? z : (i < 256 ? ms : md);
      xnext = src[(size_t)(row0 + arow) * 128 + (i & 127)];
    }
    return xnext;
  };

  // COMPUTE(s): 5 K-sub-steps from parity s&1; setprio(1) favors compute-phase waves.
  auto COMPUTE = [&](int s) {
    const char* Ac = ldsbuf + (uint32_t)(s & 1) * (uint32_t)A_BYTES;
    const size_t qoff = (size_t)s * 5u * 16384u;   // q = s*5 + ks
    __builtin_amdgcn_s_setprio(1);
#pragma unroll
    for (int ks = 0; ks < 5; ++ks) {
      bf16x8 af[4], bfr[4];
#pragma unroll
      for (int ni = 0; ni < 4; ++ni)
        bfr[ni] = *(const bf16x8*)(bpt + qoff + (size_t)ks * 16384u + (size_t)ni * 512u);
#pragma unroll
      for (int mi = 0; mi < 4; ++mi)
        af[mi] = *(const bf16x8*)(Ac + ((rA + (uint32_t)(mi * 16) * A_STRIDE_B + ks * 64u) ^ fA));
#pragma unroll
      for (int mi = 0; mi < 4; ++mi)
#pragma unroll
        for (int ni = 0; ni < 4; ++ni)
          acc[mi][ni] = __builtin_amdgcn_mfma_f32_16x16x32_bf16(af[mi], bfr[ni], acc[mi][ni], 0, 0, 0);
    }
    __builtin_amdgcn_s_setprio(0);
  };

  // ---- prologue: stage A(0); x(1) into xv0
  float xv0;
  {
    float x0 = z[(size_t)(row0 + arow) * 128 + isl];   // s=0 -> i=isl<128 -> z
    xv0 = AGEN(0, x0);
  }
  __syncthreads();

  for (int s = 0; s < NSTEP; ++s) {
    float xn = 0.f;
    if (wv & 1) {
      COMPUTE(s);
      if (s + 1 < NSTEP) xn = AGEN(s + 1, xv0);
    } else {
      if (s + 1 < NSTEP) xn = AGEN(s + 1, xv0);
      COMPUTE(s);
    }
    __syncthreads();   // one barrier: A(s+1) writes visible; parity s safe to overwrite
    xv0 = xn;
  }

  // ---- epilogue: tanh -> bf16 h (each row written entirely by one block)
#pragma unroll
  for (int mi = 0; mi < 4; ++mi)
#pragma unroll
    for (int ni = 0; ni < 4; ++ni)
#pragma unroll
      for (int rg = 0; rg < 4; ++rg) {
        int grow = row0 + mi * 16 + lhi * 4 + rg;
        int gcol = wc * 64 + ni * 16 + l16;
        hout[(size_t)grow * HID + gcol] = f2bf(fast_tanh(acc[mi][ni][rg]));
      }
}

// ---------------- kfinal (MFMA): 64 rows/block, all 64 output cols ----------------
__global__ __launch_bounds__(256) void kfinal(const unsigned short* __restrict__ h,
                                              const float* __restrict__ lw,
                                              const float* __restrict__ lb,
                                              float* __restrict__ out) {
  __shared__ unsigned short Ws[64 * 512];
  char* WsB = (char*)Ws;
  const int tid  = threadIdx.x;
  const int lane = tid & 63;
  const int wv   = tid >> 6;
  const int l16  = lane & 15;
  const int lhi  = lane >> 4;
  const int row0 = blockIdx.x * 64;

#pragma unroll
  for (int it = 0; it < 16; ++it) {
    int c = it * 256 + tid;
    int r = c >> 6;
    int k8 = (c & 63) * 8;
    const float* g = lw + r * 512 + k8;
    float4 f0 = *(const float4*)g;
    float4 f1 = *(const float4*)(g + 4);
    union { unsigned short s[8]; bf16x8 v; } u;
    u.s[0] = f2bf(f0.x); u.s[1] = f2bf(f0.y); u.s[2] = f2bf(f0.z); u.s[3] = f2bf(f0.w);
    u.s[4] = f2bf(f1.x); u.s[5] = f2bf(f1.y); u.s[6] = f2bf(f1.z); u.s[7] = f2bf(f1.w);
    *(bf16x8*)(WsB + swzw((uint32_t)r * 1024u + (uint32_t)k8 * 2u)) = u.v;
  }
  __syncthreads();

  const int arow = row0 + wv * 16 + l16;
  const unsigned short* ag = h + (size_t)arow * HID + lhi * 8;
  f32x4 acc[4] = {};
#pragma unroll
  for (int ks = 0; ks < 16; ++ks) {
    bf16x8 af = *(const bf16x8*)(ag + ks * 32);
#pragma unroll
    for (int ni = 0; ni < 4; ++ni) {
      uint32_t L = (uint32_t)(ni * 16 + l16) * 1024u + (uint32_t)(ks * 64 + lhi * 16);
      bf16x8 bfr = *(const bf16x8*)(WsB + swzw(L));
      acc[ni] = __builtin_amdgcn_mfma_f32_16x16x32_bf16(af, bfr, acc[ni], 0, 0, 0);
    }
  }
#pragma unroll
  for (int ni = 0; ni < 4; ++ni) {
    int col = ni * 16 + l16;
    float bias = lb[col];
#pragma unroll
    for (int rg = 0; rg < 4; ++rg) {
      int grow = row0 + wv * 16 + lhi * 4 + rg;
      out[(size_t)grow * 64 + col] = acc[ni][rg] + bias;
    }
  }
}

extern "C" void kernel_launch(void* const* d_in, const int* in_sizes, int n_in,
                              void* d_out, int out_size, void* d_ws, size_t ws_size,
                              hipStream_t stream) {
  const float* z  = (const float*)d_in[0];
  const float* ms = (const float*)d_in[1];
  const float* md = (const float*)d_in[2];
  const float* bw = (const float*)d_in[3];
  const float* sw = (const float*)d_in[4];
  const float* lw = (const float*)d_in[5];
  const float* lb = (const float*)d_in[6];
  float* out = (float*)d_out;

  unsigned short* Wf = (unsigned short*)d_ws;                        // 7.5 MiB fragment-linear W
  unsigned short* hb = (unsigned short*)((char*)d_ws + (8u << 20));  // 32 MiB bf16 h [32768][512]

  (void)hipFuncSetAttribute((const void*)kgemm1,
                            hipFuncAttributeMaxDynamicSharedMemorySize, LDS_BYTES);

  kpack<<<(HID * IN_DIM) / 256, 256, 0, stream>>>(bw, sw, Wf);
  kgemm1<<<512, 512, LDS_BYTES, stream>>>(z, ms, md, Wf, hb);
  kfinal<<<32768 / 64, 256, 0, stream>>>(hb, lw, lb, out);
}

// Round 23
// 242.979 us; speedup vs baseline: 1.2560x; 1.2560x over previous
//
#include <hip/hip_runtime.h>
#include <hip/hip_bf16.h>
#include <cstdint>

#define DI __device__ __forceinline__

using bf16x8 = __attribute__((ext_vector_type(8))) short;
using f32x4  = __attribute__((ext_vector_type(4))) float;

constexpr int IN_DIM = 384;
constexpr int HID    = 512;
constexpr int KTOT   = IN_DIM * 20;          // 7680: k = i*20 + t
constexpr int BM = 64, BN = 512, BK = 160;   // 8 input dims per K-step; BN = full HID
constexpr int NSTEP = KTOT / BK;             // 48
// R21 champion (257.0 us) + branchless AGEN: AGEN(s+1) and COMPUTE(s) are data-
// independent (write parity s+1 vs read parity s); removing the NSTEP guard puts them
// in one basic block so the backend scheduler can interleave B-fragment loads / MFMA
// with AGEN's VALU+ds_write. Extra step-48 AGEN writes an unread tile (memory-safe).
// A: double-buffered LDS, stride 320 + bijective XOR (addr^(row&7)<<4) write & read.
// B: fragment-linear global (L2-resident scan), coalesced 1KB frag loads.
constexpr int A_STRIDE_B = 320;
constexpr int A_BYTES    = BM * A_STRIDE_B;        // 20480
constexpr int LDS_BYTES  = 2 * A_BYTES;            // 40960 -> 2 blocks/CU (16 waves)

DI unsigned short f2bf(float f) {
  union { float f; uint32_t u; } v; v.f = f;
  uint32_t r = (v.u + 0x7FFFu + ((v.u >> 16) & 1u)) >> 16;
  return (unsigned short)r;
}
DI float fast_tanh(float x) {
  float e = __expf(2.0f * x);
  return 1.0f - 2.0f / (e + 1.0f);
}
DI uint32_t swzw(uint32_t L) { return L ^ ((L >> 6) & 0x70u); }

// ---------------- kpack: W -> bf16 fragment-linear Wf (16x16x32 layout, R18-verbatim) ----
__global__ __launch_bounds__(256) void kpack(const float* __restrict__ bw,
                                             const float* __restrict__ sw,
                                             unsigned short* __restrict__ Wf) {
  int idx = blockIdx.x * 256 + threadIdx.x;   // o*384 + i
  int o = idx / IN_DIM;
  int i = idx - o * IN_DIM;
  const float* sp = sw + (size_t)idx * 19;
  const uint32_t gq  = (uint32_t)(o >> 4);
  const uint32_t l16o = (uint32_t)(o & 15);
#pragma unroll
  for (int c = 0; c < 20; ++c) {
    int k = i * 20 + c;
    uint32_t q  = (uint32_t)k >> 5;
    uint32_t kr = (uint32_t)k & 31u;
    uint32_t lane = l16o + ((kr >> 3) << 4);
    uint32_t off = (q * 32u + gq) * 512u + lane * 8u + (kr & 7u);
    float v = (c == 0) ? bw[idx] : sp[c - 1];
    Wf[off] = f2bf(v);
  }
}

// ---------------- fused KAN GEMM: h = tanh(A(x) @ W^T), 8 waves, wave tile 64x64 ----------------
__global__ __launch_bounds__(512, 4) void kgemm1(const float* __restrict__ z,
                                                 const float* __restrict__ ms,
                                                 const float* __restrict__ md,
                                                 const unsigned short* __restrict__ Wf,
                                                 unsigned short* __restrict__ hout) {
  extern __shared__ char ldsbuf[];            // [A0 @0][A1 @20480]

  const int tid  = threadIdx.x;
  const int lane = tid & 63;
  const int wc   = tid >> 6;                  // 0..7 : N strip (64 cols); all waves share rows
  const int l16  = lane & 15;
  const int lhi  = lane >> 4;

  // XCD-aware bijective swizzle: grid 512 = 8 XCD * 64 (pure M split; every block scans W)
  int wg = blockIdx.x;
  int id = (wg & 7) * 64 + (wg >> 3);
  const int row0 = id * BM;

  // B global fragment base: g = wc*4 + ni in [0,32); q = s*5 + ks (frag stride 16384 elems)
  const unsigned short* bpt = Wf + (size_t)(wc * 4) * 512 + (size_t)lane * 8;

  // A-gen: exactly ONE task per thread (64 rows x 8 isl = 512)
  const int isl = tid & 7;
  const int arow = tid >> 3;                  // 0..63
  const uint32_t fw = ((uint32_t)arow & 7u) << 4;
  const uint32_t abase = (uint32_t)arow * A_STRIDE_B + (uint32_t)isl * 40u;

  // A fragment read base (XOR applied to full address; R18-verbatim)
  const uint32_t fA = (uint32_t)(l16 & 7) << 4;      // row&7 = l16&7
  const uint32_t rA = (uint32_t)l16 * A_STRIDE_B + (uint32_t)lhi * 16u;

  f32x4 acc[4][4] = {};

  // ---- prologue: stage A(0) into parity 0; prefetch x(1)
  float xv0;
  {
    float x = z[(size_t)(row0 + arow) * 128 + isl];   // s=0 -> i=isl<128 -> z
    float xt = fast_tanh(x);
    float tt = (xt + 1.0f) * 8.0f;
    int   m  = (int)tt; m = m > 16 ? 16 : m;
    float u  = tt - (float)m;
    float omu = 1.0f - u;
    float u2 = u * u, u3 = u2 * u;
    float w0 = omu * omu * omu * (1.0f / 6.0f);
    float w1 = (3.0f * u3 - 6.0f * u2 + 4.0f) * (1.0f / 6.0f);
    float w2 = (-3.0f * u3 + 3.0f * u2 + 3.0f * u + 1.0f) * (1.0f / 6.0f);
    float w3 = u3 * (1.0f / 6.0f);
    float sil = xt / (1.0f + __expf(-xt));
#pragma unroll
    for (int zz = 0; zz < 5; ++zz)
      *(uint64_t*)(ldsbuf + ((abase + zz * 8) ^ fw)) = 0ull;
    *(short*)(ldsbuf + (abase ^ fw)) = (short)f2bf(sil);
    *(short*)(ldsbuf + ((abase + 2u * (m + 1)) ^ fw)) = (short)f2bf(w0);
    *(short*)(ldsbuf + ((abase + 2u * (m + 2)) ^ fw)) = (short)f2bf(w1);
    *(short*)(ldsbuf + ((abase + 2u * (m + 3)) ^ fw)) = (short)f2bf(w2);
    if (m < 16)
      *(short*)(ldsbuf + ((abase + 2u * (m + 4)) ^ fw)) = (short)f2bf(w3);
    xv0 = z[(size_t)(row0 + arow) * 128 + 8 + isl];   // x(1)
  }
  __syncthreads();

  for (int s = 0; s < NSTEP; ++s) {
    const uint32_t pc = (uint32_t)(s & 1);
    const uint32_t pn = pc ^ 1u;
    char* An = ldsbuf + pn * (uint32_t)A_BYTES;
    const char* Ac = ldsbuf + pc * (uint32_t)A_BYTES;

    // ---- stage A(s+1) into An using xv0 = x(s+1) -- UNCONDITIONAL (branchless with
    // COMPUTE below so the scheduler can interleave; step-48 tile is unread, reads safe)
    {
      float xt = fast_tanh(xv0);
      float tt = (xt + 1.0f) * 8.0f;
      int   m  = (int)tt; m = m > 16 ? 16 : m;
      float u  = tt - (float)m;
      float omu = 1.0f - u;
      float u2 = u * u, u3 = u2 * u;
      float w0 = omu * omu * omu * (1.0f / 6.0f);
      float w1 = (3.0f * u3 - 6.0f * u2 + 4.0f) * (1.0f / 6.0f);
      float w2 = (-3.0f * u3 + 3.0f * u2 + 3.0f * u + 1.0f) * (1.0f / 6.0f);
      float w3 = u3 * (1.0f / 6.0f);
      float sil = xt / (1.0f + __expf(-xt));
#pragma unroll
      for (int zz = 0; zz < 5; ++zz)
        *(uint64_t*)(An + ((abase + zz * 8) ^ fw)) = 0ull;
      *(short*)(An + (abase ^ fw)) = (short)f2bf(sil);
      *(short*)(An + ((abase + 2u * (m + 1)) ^ fw)) = (short)f2bf(w0);
      *(short*)(An + ((abase + 2u * (m + 2)) ^ fw)) = (short)f2bf(w1);
      *(short*)(An + ((abase + 2u * (m + 3)) ^ fw)) = (short)f2bf(w2);
      if (m < 16)
        *(short*)(An + ((abase + 2u * (m + 4)) ^ fw)) = (short)f2bf(w3);
    }
    // ---- prefetch x(s+2), branchless: index wraps mod IN_DIM (wrapped value unused)
    float xn0;
    {
      int i = (s + 2) * 8 + isl;
      i = (i >= IN_DIM) ? (i - IN_DIM) : i;
      const float* src = (i < 128) ? z : (i < 256 ? ms : md);
      xn0 = src[(size_t)(row0 + arow) * 128 + (i & 127)];
    }

    // ---- compute(s): A frags from LDS (parity pc), B frags as coalesced 1KB global loads
    const size_t qoff = (size_t)s * 5u * 16384u;   // q = s*5 + ks
#pragma unroll
    for (int ks = 0; ks < 5; ++ks) {
      bf16x8 af[4], bfr[4];
#pragma unroll
      for (int ni = 0; ni < 4; ++ni)
        bfr[ni] = *(const bf16x8*)(bpt + qoff + (size_t)ks * 16384u + (size_t)ni * 512u);
#pragma unroll
      for (int mi = 0; mi < 4; ++mi)
        af[mi] = *(const bf16x8*)(Ac + ((rA + (uint32_t)(mi * 16) * A_STRIDE_B + ks * 64u) ^ fA));
#pragma unroll
      for (int mi = 0; mi < 4; ++mi)
#pragma unroll
        for (int ni = 0; ni < 4; ++ni)
          acc[mi][ni] = __builtin_amdgcn_mfma_f32_16x16x32_bf16(af[mi], bfr[ni], acc[mi][ni], 0, 0, 0);
    }

    __syncthreads();   // one barrier: A(s+1) writes visible; Ac safe to overwrite next step
    xv0 = xn0;
  }

  // ---- epilogue: tanh -> bf16 h (each row written entirely by one block)
#pragma unroll
  for (int mi = 0; mi < 4; ++mi)
#pragma unroll
    for (int ni = 0; ni < 4; ++ni)
#pragma unroll
      for (int rg = 0; rg < 4; ++rg) {
        int grow = row0 + mi * 16 + lhi * 4 + rg;
        int gcol = wc * 64 + ni * 16 + l16;
        hout[(size_t)grow * HID + gcol] = f2bf(fast_tanh(acc[mi][ni][rg]));
      }
}

// ---------------- kfinal (MFMA): 64 rows/block, all 64 output cols ----------------
__global__ __launch_bounds__(256) void kfinal(const unsigned short* __restrict__ h,
                                              const float* __restrict__ lw,
                                              const float* __restrict__ lb,
                                              float* __restrict__ out) {
  __shared__ unsigned short Ws[64 * 512];
  char* WsB = (char*)Ws;
  const int tid  = threadIdx.x;
  const int lane = tid & 63;
  const int wv   = tid >> 6;
  const int l16  = lane & 15;
  const int lhi  = lane >> 4;
  const int row0 = blockIdx.x * 64;

#pragma unroll
  for (int it = 0; it < 16; ++it) {
    int c = it * 256 + tid;
    int r = c >> 6;
    int k8 = (c & 63) * 8;
    const float* g = lw + r * 512 + k8;
    float4 f0 = *(const float4*)g;
    float4 f1 = *(const float4*)(g + 4);
    union { unsigned short s[8]; bf16x8 v; } u;
    u.s[0] = f2bf(f0.x); u.s[1] = f2bf(f0.y); u.s[2] = f2bf(f0.z); u.s[3] = f2bf(f0.w);
    u.s[4] = f2bf(f1.x); u.s[5] = f2bf(f1.y); u.s[6] = f2bf(f1.z); u.s[7] = f2bf(f1.w);
    *(bf16x8*)(WsB + swzw((uint32_t)r * 1024u + (uint32_t)k8 * 2u)) = u.v;
  }
  __syncthreads();

  const int arow = row0 + wv * 16 + l16;
  const unsigned short* ag = h + (size_t)arow * HID + lhi * 8;
  f32x4 acc[4] = {};
#pragma unroll
  for (int ks = 0; ks < 16; ++ks) {
    bf16x8 af = *(const bf16x8*)(ag + ks * 32);
#pragma unroll
    for (int ni = 0; ni < 4; ++ni) {
      uint32_t L = (uint32_t)(ni * 16 + l16) * 1024u + (uint32_t)(ks * 64 + lhi * 16);
      bf16x8 bfr = *(const bf16x8*)(WsB + swzw(L));
      acc[ni] = __builtin_amdgcn_mfma_f32_16x16x32_bf16(af, bfr, acc[ni], 0, 0, 0);
    }
  }
#pragma unroll
  for (int ni = 0; ni < 4; ++ni) {
    int col = ni * 16 + l16;
    float bias = lb[col];
#pragma unroll
    for (int rg = 0; rg < 4; ++rg) {
      int grow = row0 + wv * 16 + lhi * 4 + rg;
      out[(size_t)grow * 64 + col] = acc[ni][rg] + bias;
    }
  }
}

extern "C" void kernel_launch(void* const* d_in, const int* in_sizes, int n_in,
                              void* d_out, int out_size, void* d_ws, size_t ws_size,
                              hipStream_t stream) {
  const float* z  = (const float*)d_in[0];
  const float* ms = (const float*)d_in[1];
  const float* md = (const float*)d_in[2];
  const float* bw = (const float*)d_in[3];
  const float* sw = (const float*)d_in[4];
  const float* lw = (const float*)d_in[5];
  const float* lb = (const float*)d_in[6];
  float* out = (float*)d_out;

  unsigned short* Wf = (unsigned short*)d_ws;                        // 7.5 MiB fragment-linear W
  unsigned short* hb = (unsigned short*)((char*)d_ws + (8u << 20));  // 32 MiB bf16 h [32768][512]

  (void)hipFuncSetAttribute((const void*)kgemm1,
                            hipFuncAttributeMaxDynamicSharedMemorySize, LDS_BYTES);

  kpack<<<(HID * IN_DIM) / 256, 256, 0, stream>>>(bw, sw, Wf);
  kgemm1<<<512, 512, LDS_BYTES, stream>>>(z, ms, md, Wf, hb);
  kfinal<<<32768 / 64, 256, 0, stream>>>(hb, lw, lb, out);
}